// Round 3
// baseline (7231.861 us; speedup 1.0000x reference)
//
#include <hip/hip_runtime.h>

#define O_N 2000
#define T_N 6000
#define DIN 2048
#define DW  300
#define DG  512
#define HH_ 512

__device__ __forceinline__ float4 ld4(const float* p) { return *(const float4*)p; }

// Fused GEMM: C = act(Afetch @ W + bias). fp32 FMA within K=64 chunks,
// promoted to fp64 across chunks. Software-pipelined global->LDS staging.
// MODE 0: A plain row-major (lda)
// MODE 1: concat — col k<KA from A, else Tab[idx[r*idxStride]] (DWc wide)
// MODE 2: edge-combine — relu(P1v[s[r]]+A[r]+P2v[o[r]]+badd) elementwise
// MODE 3: pool-divide — A[r][k] * (1/max(CNT[r],1))
// Pair mode (W_alt != null): blocks with bx >= bxHalf use W_alt/C_alt
// (same N, ldc) — fuses two GEMMs sharing the A operand into one dispatch.
template<int TBM, int TBN, int MR, int NR, int MODE>
__global__ __launch_bounds__(256, 4) void gemm_k(
    const float* __restrict__ A, int lda,
    const float* __restrict__ Tab, int KA, int DWc,
    const int* __restrict__ idx, int idxStride,
    const float* __restrict__ P1v, const float* __restrict__ P2v,
    const int* __restrict__ rels, const float* __restrict__ badd,
    const int* __restrict__ CNT,
    const float* __restrict__ W, const float* __restrict__ bias, int doRelu,
    float* __restrict__ C, int ldc,
    const float* __restrict__ W_alt, float* __restrict__ C_alt, int bxHalf,
    int M, int N, int K)
{
    constexpr int TBK = 32;
    constexpr int AL = TBM / 32;        // float4 A loads per thread
    constexpr int BL = TBN / 32;        // float4 B loads per thread
    constexpr int NC4 = TBN / 4;
    __shared__ float As[TBK][TBM + 4];
    __shared__ float Bs[TBK][TBN + 4];

    const int tid = threadIdx.x;
    int bx = blockIdx.x;
    const float* Wp = W;
    float* Cp = C;
    if (W_alt != nullptr && bx >= bxHalf) { Wp = W_alt; Cp = C_alt; bx -= bxHalf; }
    const int n0 = bx * TBN, m0 = blockIdx.y * TBM;

    // ---- A-fetch assignment: f4 i = tid + l*256 over [row][kchunk] ----
    const int aKc = (tid & 7) * 4;
    int aRow[AL]; bool aOK[AL];
    const float* aP[AL]; const float* tP[AL];
    const float* p1P[AL]; const float* p2P[AL];
    float cf[AL];
#pragma unroll
    for (int l = 0; l < AL; l++) {
        aRow[l] = (tid >> 3) + l * 32;
        int r = m0 + aRow[l];
        aOK[l] = r < M;
        int rr = aOK[l] ? r : 0;
        aP[l] = A + (size_t)rr * lda;
        if constexpr (MODE == 1) tP[l] = Tab + (size_t)idx[(size_t)rr * idxStride] * DWc;
        if constexpr (MODE == 2) {
            p1P[l] = P1v + (size_t)rels[3 * rr + 0] * HH_;
            p2P[l] = P2v + (size_t)rels[3 * rr + 2] * HH_;
        }
        if constexpr (MODE == 3) { int c = CNT[rr]; cf[l] = 1.f / (float)(c < 1 ? 1 : c); }
    }
    // ---- B-fetch assignment ----
    int bK[BL], bN[BL];
#pragma unroll
    for (int l = 0; l < BL; l++) {
        int i = tid + l * 256;
        bK[l] = i / NC4;
        bN[l] = (i % NC4) * 4;
    }

    auto fetchA = [&](int k0, float4 (&pa)[AL]) {
#pragma unroll
        for (int l = 0; l < AL; l++) {
            const int k = k0 + aKc;
            float4 v = make_float4(0.f, 0.f, 0.f, 0.f);
            if (aOK[l] && k < K) {
                if constexpr (MODE == 0) {
                    v = ld4(aP[l] + k);
                } else if constexpr (MODE == 1) {
                    v = (k < KA) ? ld4(aP[l] + k) : ld4(tP[l] + (k - KA));
                } else if constexpr (MODE == 2) {
                    float4 vp = ld4(aP[l] + k), v1 = ld4(p1P[l] + k);
                    float4 v2 = ld4(p2P[l] + k), vb = ld4(badd + k);
                    v.x = fmaxf(v1.x + vp.x + v2.x + vb.x, 0.f);
                    v.y = fmaxf(v1.y + vp.y + v2.y + vb.y, 0.f);
                    v.z = fmaxf(v1.z + vp.z + v2.z + vb.z, 0.f);
                    v.w = fmaxf(v1.w + vp.w + v2.w + vb.w, 0.f);
                } else {
                    v = ld4(aP[l] + k);
                    v.x *= cf[l]; v.y *= cf[l]; v.z *= cf[l]; v.w *= cf[l];
                }
            }
            pa[l] = v;
        }
    };
    auto fetchB = [&](int k0, float4 (&pb)[BL]) {
#pragma unroll
        for (int l = 0; l < BL; l++) {
            const int k = k0 + bK[l];
            pb[l] = (k < K) ? ld4(Wp + (size_t)k * N + n0 + bN[l])
                            : make_float4(0.f, 0.f, 0.f, 0.f);
        }
    };
    auto storeAB = [&](float4 (&pa)[AL], float4 (&pb)[BL]) {
#pragma unroll
        for (int l = 0; l < AL; l++) {
            As[aKc + 0][aRow[l]] = pa[l].x;
            As[aKc + 1][aRow[l]] = pa[l].y;
            As[aKc + 2][aRow[l]] = pa[l].z;
            As[aKc + 3][aRow[l]] = pa[l].w;
        }
#pragma unroll
        for (int l = 0; l < BL; l++)
            *(float4*)&Bs[bK[l]][bN[l]] = pb[l];
    };

    const int tx = tid & 15, ty = tid >> 4;
    float  facc[MR][NR];
    double dacc[MR][NR];
#pragma unroll
    for (int i = 0; i < MR; i++)
#pragma unroll
        for (int j = 0; j < NR; j++) { facc[i][j] = 0.f; dacc[i][j] = 0.0; }

    const int tiles = (K + TBK - 1) / TBK;
    float4 pa[AL], pb[BL];
    fetchA(0, pa);
    fetchB(0, pb);

    for (int t = 0; t < tiles; t++) {
        __syncthreads();                    // prev compute done
        storeAB(pa, pb);
        __syncthreads();
        if (t + 1 < tiles) {                // prefetch next tile during compute
            fetchA((t + 1) * TBK, pa);
            fetchB((t + 1) * TBK, pb);
        }
#pragma unroll
        for (int kk = 0; kk < TBK; kk++) {
            float br[NR], ar[MR];
            if constexpr (NR == 4) {
                float4 b = *(const float4*)&Bs[kk][tx * NR];
                br[0] = b.x; br[1] = b.y; br[2] = b.z; br[3] = b.w;
            } else {
                float2 b = *(const float2*)&Bs[kk][tx * NR];
                br[0] = b.x; br[1] = b.y;
            }
            if constexpr (MR == 4) {
                float4 a = *(const float4*)&As[kk][ty * MR];
                ar[0] = a.x; ar[1] = a.y; ar[2] = a.z; ar[3] = a.w;
            } else {
                float2 a = *(const float2*)&As[kk][ty * MR];
                ar[0] = a.x; ar[1] = a.y;
            }
#pragma unroll
            for (int i = 0; i < MR; i++)
#pragma unroll
                for (int j = 0; j < NR; j++)
                    facc[i][j] = fmaf(ar[i], br[j], facc[i][j]);
        }
        if ((t & 1) || (t == tiles - 1)) {   // promote every 2 tiles (K=64)
#pragma unroll
            for (int i = 0; i < MR; i++)
#pragma unroll
                for (int j = 0; j < NR; j++) {
                    dacc[i][j] += (double)facc[i][j];
                    facc[i][j] = 0.f;
                }
        }
    }

    // ---- epilogue ----
#pragma unroll
    for (int i = 0; i < MR; i++) {
        const int row = m0 + ty * MR + i;
        if (row < M) {
            float v[NR];
#pragma unroll
            for (int j = 0; j < NR; j++) {
                double x = dacc[i][j];
                if (bias) x += (double)bias[n0 + tx * NR + j];
                float f = (float)x;
                if (doRelu) f = fmaxf(f, 0.f);
                v[j] = f;
            }
            float* dst = Cp + (size_t)row * ldc + n0 + tx * NR;
            if constexpr (NR == 4) {
                float4 o; o.x = v[0]; o.y = v[1]; o.z = v[2]; o.w = v[3];
                *(float4*)dst = o;
            } else {
                float2 o; o.x = v[0]; o.y = v[1];
                *(float2*)dst = o;
            }
        }
    }
}

__global__ void count_edges(const int* __restrict__ rels, int* __restrict__ CNT)
{
    int e = blockIdx.x * 256 + threadIdx.x;
    if (e >= T_N) return;
    atomicAdd(CNT + rels[3 * e + 0], 1);
    atomicAdd(CNT + rels[3 * e + 2], 1);
}

// pooled[s[e]] += t2[e,0:512]; pooled[o[e]] += t2[e,1024:1536]  (fp32 HW atomics)
__global__ void scatter_pool(const float* __restrict__ T2,
                             const int* __restrict__ rels,
                             float* __restrict__ PO)
{
    int e = blockIdx.x;
    int t = threadIdx.x;            // 256
    int s = rels[e * 3 + 0];
    int o = rels[e * 3 + 2];
#pragma unroll
    for (int u = 0; u < 2; u++) {
        int j = t + u * 256;
        unsafeAtomicAdd(PO + (size_t)s * HH_ + j, T2[(size_t)e * 1536 + j]);
        unsafeAtomicAdd(PO + (size_t)o * HH_ + j, T2[(size_t)e * 1536 + 1024 + j]);
    }
}

// dst[e, 0:512] = T2[e, 512:1024]
__global__ void copy_pred(const float* __restrict__ T2, float* __restrict__ dst)
{
    int i = blockIdx.x * 256 + threadIdx.x;   // float4 index
    if (i >= T_N * HH_ / 4) return;
    int e = i / (HH_ / 4);
    int j = (i % (HH_ / 4)) << 2;
    float4 v = *(const float4*)(T2 + (size_t)e * 1536 + 512 + j);
    *(float4*)(dst + (size_t)e * HH_ + j) = v;
}

template<int TBM, int TBN, int MR, int NR, int MODE>
static inline void G(hipStream_t st, const float* A, int lda,
                     const float* Tab, int KA, int DWc,
                     const int* idx, int idxs,
                     const float* P1v, const float* P2v,
                     const int* rels, const float* badd, const int* CNT,
                     const float* W, const float* bias, int relu_,
                     float* C, int ldc,
                     const float* W_alt, float* C_alt,
                     int M, int N, int K)
{
    int bxHalf = N / TBN;
    dim3 g(bxHalf * (W_alt ? 2 : 1), (M + TBM - 1) / TBM), b(256);
    gemm_k<TBM, TBN, MR, NR, MODE><<<g, b, 0, st>>>(
        A, lda, Tab, KA, DWc, idx, idxs, P1v, P2v, rels, badd, CNT,
        W, bias, relu_, C, ldc, W_alt, C_alt, bxHalf, M, N, K);
}

extern "C" void kernel_launch(void* const* d_in, const int* in_sizes, int n_in,
                              void* d_out, int out_size, void* d_ws, size_t ws_size,
                              hipStream_t stream)
{
    const float* obj_embs  = (const float*)d_in[0];
    const float* pred_embs = (const float*)d_in[2];
    const int*   rels      = (const int*)d_in[4];
    const int*   objs      = (const int*)d_in[5];
    const float* obj_table = (const float*)d_in[6];
    const float* rel_table = (const float*)d_in[7];
    const float* Wf_obj = (const float*)d_in[8];
    const float* bf_obj = (const float*)d_in[9];
    const float* Wf_rel = (const float*)d_in[10];
    const float* bf_rel = (const float*)d_in[11];
    const float* W1a = (const float*)d_in[12];
    const float* b1a = (const float*)d_in[13];
    const float* W1b = (const float*)d_in[14];
    const float* b1b = (const float*)d_in[15];
    const float* W2a = (const float*)d_in[16];
    const float* b2a = (const float*)d_in[17];
    const float* W2b = (const float*)d_in[18];
    const float* b2b = (const float*)d_in[19];
    const float* Ws1a = (const float*)d_in[20];
    const float* bs1a = (const float*)d_in[21];
    const float* Ws1b = (const float*)d_in[22];
    const float* bs1b = (const float*)d_in[23];
    const float* Ws2a = (const float*)d_in[24];
    const float* bs2a = (const float*)d_in[25];
    const float* Ws2b = (const float*)d_in[26];
    const float* bs2b = (const float*)d_in[27];
    float* out = (float*)d_out;

    // workspace layout (fp32), ~127 MB
    float* base = (float*)d_ws;
    float* OV = base;                              // 2000*2048
    float* PV = OV + (size_t)O_N * DIN;            // 6000*2048
    float* P1 = PV + (size_t)T_N * DIN;            // 2000*512
    float* P2 = P1 + (size_t)O_N * HH_;            // 2000*512
    float* PP = P2 + (size_t)O_N * HH_;            // 6000*512
    float* T2 = PP + (size_t)T_N * HH_;            // 6000*1536
    float* PO = T2 + (size_t)T_N * 1536;           // 2000*512
    int* CNT = (int*)(PO + (size_t)O_N * HH_);     // 2000 ints

    // edge counts — s,o fixed for the whole call, compute once
    hipMemsetAsync(CNT, 0, (size_t)O_N * sizeof(int), stream);
    hipLaunchKernelGGL(count_edges, dim3((T_N + 255) / 256), dim3(256), 0, stream,
                       rels, CNT);

    // input projections (concat with table lookup fused into A-load)
    G<64, 64, 4, 4, 1>(stream, obj_embs, DIN, obj_table, DIN, DW, objs, 1,
                       nullptr, nullptr, nullptr, nullptr, nullptr,
                       Wf_obj, bf_obj, 1, OV, DIN, nullptr, nullptr,
                       O_N, DIN, DIN + DW);
    G<64, 64, 4, 4, 1>(stream, pred_embs, DIN, rel_table, DIN, DW, rels + 1, 3,
                       nullptr, nullptr, nullptr, nullptr, nullptr,
                       Wf_rel, bf_rel, 1, PV, DIN, nullptr, nullptr,
                       T_N, DIN, DIN + DW);

    for (int L = 0; L < 5; L++) {
        const int D = (L == 0) ? DIN : HH_;
        const float* w1a  = (L == 0) ? W1a : (Ws1a + (size_t)(L - 1) * 3 * HH_ * HH_);
        const float* bb1a = (L == 0) ? b1a : (bs1a + (size_t)(L - 1) * HH_);
        const float* w1b  = (L == 0) ? W1b : (Ws1b + (size_t)(L - 1) * HH_ * 1536);
        const float* bb1b = (L == 0) ? b1b : (bs1b + (size_t)(L - 1) * 1536);
        const float* w2a  = (L == 0) ? W2a : (Ws2a + (size_t)(L - 1) * HH_ * HH_);
        const float* bb2a = (L == 0) ? b2a : (bs2a + (size_t)(L - 1) * HH_);
        const float* w2b  = (L == 0) ? W2b : (Ws2b + (size_t)(L - 1) * HH_ * DG);
        const float* bb2b = (L == 0) ? b2b : (bs2b + (size_t)(L - 1) * DG);
        const float* w1a_top = w1a;
        const float* w1a_mid = w1a + (size_t)D * HH_;
        const float* w1a_bot = w1a + (size_t)2 * D * HH_;

        // P1 = OV@top, P2 = OV@bot — fused pair dispatch (shared A operand)
        G<64, 64, 4, 4, 0>(stream, OV, D, nullptr, 0, 0, nullptr, 0,
                           nullptr, nullptr, nullptr, nullptr, nullptr,
                           w1a_top, nullptr, 0, P1, HH_, w1a_bot, P2,
                           O_N, HH_, D);
        // PP = PV@mid
        G<64, 64, 4, 4, 0>(stream, PV, D, nullptr, 0, 0, nullptr, 0,
                           nullptr, nullptr, nullptr, nullptr, nullptr,
                           w1a_mid, nullptr, 0, PP, HH_, nullptr, nullptr,
                           T_N, HH_, D);

        // t2 = relu( relu(P1[s]+PP+P2[o]+b1a) @ W1b + b1b ) — edge-combine fused
        G<64, 64, 4, 4, 2>(stream, PP, HH_, nullptr, 0, 0, nullptr, 0,
                           P1, P2, rels, bb1a, nullptr,
                           w1b, bb1b, 1, T2, 1536, nullptr, nullptr,
                           T_N, 1536, HH_);

        // pooling (fp32 HW atomics)
        hipMemsetAsync(PO, 0, (size_t)O_N * HH_ * sizeof(float), stream);
        hipLaunchKernelGGL(scatter_pool, dim3(T_N), dim3(256), 0, stream,
                           T2, rels, PO);

        // obj MLP2 (small-M: 32x32 tiles for block-count) — pool-div fused
        G<32, 32, 2, 2, 3>(stream, PO, HH_, nullptr, 0, 0, nullptr, 0,
                           nullptr, nullptr, nullptr, nullptr, CNT,
                           w2a, bb2a, 1, P1, HH_, nullptr, nullptr,
                           O_N, HH_, HH_);
        float* objDst = (L == 4) ? out : OV;
        G<32, 32, 2, 2, 0>(stream, P1, HH_, nullptr, 0, 0, nullptr, 0,
                           nullptr, nullptr, nullptr, nullptr, nullptr,
                           w2b, bb2b, 1, objDst, HH_, nullptr, nullptr,
                           O_N, DG, HH_);

        float* predDst = (L == 4) ? (out + (size_t)O_N * DG) : PV;
        hipLaunchKernelGGL(copy_pred, dim3((T_N * HH_ / 4 + 255) / 256), dim3(256), 0, stream,
                           T2, predDst);
    }
}

// Round 4
// 3551.991 us; speedup vs baseline: 2.0360x; 2.0360x over previous
//
#include <hip/hip_runtime.h>

#define O_N 2000
#define T_N 6000
#define DIN 2048
#define DW  300
#define DG  512
#define HH_ 512

__device__ __forceinline__ float4 ld4(const float* p) { return *(const float4*)p; }

// C = act(Afetch @ W + bias). fp32 FMA within K=64 chunks, fp64 across chunks.
// Register-prefetch pipeline, one A-row per staging thread (no pointer arrays).
// MODE 0: plain A (lda)       MODE 1: concat A | Tab[idx[r]]
// MODE 2: relu(P1v[s[r]]+A[r]+P2v[o[r]]+badd)   MODE 3: A[r]*(1/max(CNT[r],1))
// Pair mode (W_alt): bx >= bxHalf uses W_alt/C_alt (same N, ldc).
template<int TBM, int TBN, int MR, int NR, int MODE>
__global__ __launch_bounds__(256) void gemm_k(
    const float* __restrict__ A, int lda,
    const float* __restrict__ Tab, int KA, int DWc,
    const int* __restrict__ idx, int idxStride,
    const float* __restrict__ P1v, const float* __restrict__ P2v,
    const int* __restrict__ rels, const float* __restrict__ badd,
    const int* __restrict__ CNT,
    const float* __restrict__ W, const float* __restrict__ bias, int doRelu,
    float* __restrict__ C, int ldc,
    const float* __restrict__ W_alt, float* __restrict__ C_alt, int bxHalf,
    int M, int N, int K)
{
    constexpr int TBK = 16;
    constexpr int TPR = 256 / TBM;            // staging threads per A row
    constexpr int AF  = TBK / TPR / 4;        // float4 A loads per thread
    constexpr bool B4 = (TBN * TBK) >= 1024;  // B staged as float4 else float2
    static_assert(TBM / MR == 16 && TBN / NR == 16, "16x16 thread tile");

    __shared__ float As[TBK][TBM + 4];
    __shared__ float Bs[TBK][TBN + 4];

    const int tid = threadIdx.x;
    int bx = blockIdx.x;
    const float* Wp = W;
    float* Cp = C;
    if (W_alt != nullptr && bx >= bxHalf) { Wp = W_alt; Cp = C_alt; bx -= bxHalf; }
    const int n0 = bx * TBN, m0 = blockIdx.y * TBM;

    // ---- A staging: one row, AF float4's ----
    const int aRow = tid / TPR;
    const int aKc  = (tid % TPR) * (TBK / TPR);
    const int r = m0 + aRow;
    const bool rOK = r < M;
    const int rr = rOK ? r : 0;
    const float* aP  = A + (size_t)rr * lda;
    const float* tP  = nullptr;
    const float* p1P = nullptr;
    const float* p2P = nullptr;
    float cf = 1.f;
    if constexpr (MODE == 1) tP = Tab + (size_t)idx[(size_t)rr * idxStride] * DWc;
    if constexpr (MODE == 2) {
        p1P = P1v + (size_t)rels[3 * rr + 0] * HH_;
        p2P = P2v + (size_t)rels[3 * rr + 2] * HH_;
    }
    if constexpr (MODE == 3) { int c = CNT[rr]; cf = 1.f / (float)(c < 1 ? 1 : c); }

    // ---- B staging ----
    const int bK = tid >> 4;
    const int bN = B4 ? ((tid & 15) << 2) : ((tid & 15) << 1);

    auto fetchA1 = [&](int k) -> float4 {
        float4 v = make_float4(0.f, 0.f, 0.f, 0.f);
        if (rOK && k < K) {
            if constexpr (MODE == 0) {
                v = ld4(aP + k);
            } else if constexpr (MODE == 1) {
                v = (k < KA) ? ld4(aP + k) : ld4(tP + (k - KA));
            } else if constexpr (MODE == 2) {
                float4 vp = ld4(aP + k), v1 = ld4(p1P + k);
                float4 v2 = ld4(p2P + k), vb = ld4(badd + k);
                v.x = fmaxf(v1.x + vp.x + v2.x + vb.x, 0.f);
                v.y = fmaxf(v1.y + vp.y + v2.y + vb.y, 0.f);
                v.z = fmaxf(v1.z + vp.z + v2.z + vb.z, 0.f);
                v.w = fmaxf(v1.w + vp.w + v2.w + vb.w, 0.f);
            } else {
                v = ld4(aP + k);
                v.x *= cf; v.y *= cf; v.z *= cf; v.w *= cf;
            }
        }
        return v;
    };

    float4 pa[AF];
    float4 pb4;
    float2 pb2;

    auto fetchAll = [&](int k0) {
#pragma unroll
        for (int l = 0; l < AF; l++) pa[l] = fetchA1(k0 + aKc + 4 * l);
        const int kb = k0 + bK;
        if constexpr (B4) {
            pb4 = (kb < K) ? ld4(Wp + (size_t)kb * N + n0 + bN)
                           : make_float4(0.f, 0.f, 0.f, 0.f);
        } else {
            pb2 = (kb < K) ? *(const float2*)(Wp + (size_t)kb * N + n0 + bN)
                           : make_float2(0.f, 0.f);
        }
    };
    auto storeAll = [&]() {
#pragma unroll
        for (int l = 0; l < AF; l++) {
            As[aKc + 4 * l + 0][aRow] = pa[l].x;
            As[aKc + 4 * l + 1][aRow] = pa[l].y;
            As[aKc + 4 * l + 2][aRow] = pa[l].z;
            As[aKc + 4 * l + 3][aRow] = pa[l].w;
        }
        if constexpr (B4) *(float4*)&Bs[bK][bN] = pb4;
        else              *(float2*)&Bs[bK][bN] = pb2;
    };

    const int tx = tid & 15, ty = tid >> 4;
    float  facc[MR][NR];
    double dacc[MR][NR];
#pragma unroll
    for (int i = 0; i < MR; i++)
#pragma unroll
        for (int j = 0; j < NR; j++) { facc[i][j] = 0.f; dacc[i][j] = 0.0; }

    const int tiles = (K + TBK - 1) / TBK;
    fetchAll(0);

    for (int t = 0; t < tiles; t++) {
        __syncthreads();
        storeAll();
        __syncthreads();
        if (t + 1 < tiles) fetchAll((t + 1) * TBK);

#pragma unroll
        for (int kk = 0; kk < TBK; kk++) {
            float ar[MR], br[NR];
#pragma unroll
            for (int mi = 0; mi < MR / 4; mi++) {
                float4 a = *(const float4*)&As[kk][ty * MR + 4 * mi];
                ar[4 * mi + 0] = a.x; ar[4 * mi + 1] = a.y;
                ar[4 * mi + 2] = a.z; ar[4 * mi + 3] = a.w;
            }
            if constexpr (NR == 4) {
                float4 b = *(const float4*)&Bs[kk][tx * NR];
                br[0] = b.x; br[1] = b.y; br[2] = b.z; br[3] = b.w;
            } else {
                float2 b = *(const float2*)&Bs[kk][tx * NR];
                br[0] = b.x; br[1] = b.y;
            }
#pragma unroll
            for (int i = 0; i < MR; i++)
#pragma unroll
                for (int j = 0; j < NR; j++)
                    facc[i][j] = fmaf(ar[i], br[j], facc[i][j]);
        }
        if (((t & 3) == 3) || (t == tiles - 1)) {   // promote every 4 tiles (K=64)
#pragma unroll
            for (int i = 0; i < MR; i++)
#pragma unroll
                for (int j = 0; j < NR; j++) {
                    dacc[i][j] += (double)facc[i][j];
                    facc[i][j] = 0.f;
                }
        }
    }

    // ---- epilogue ----
#pragma unroll
    for (int i = 0; i < MR; i++) {
        const int row = m0 + ty * MR + i;
        if (row < M) {
            float v[NR];
#pragma unroll
            for (int j = 0; j < NR; j++) {
                double x = dacc[i][j];
                if (bias) x += (double)bias[n0 + tx * NR + j];
                float f = (float)x;
                if (doRelu) f = fmaxf(f, 0.f);
                v[j] = f;
            }
            float* dst = Cp + (size_t)row * ldc + n0 + tx * NR;
            if constexpr (NR == 4) {
                float4 o; o.x = v[0]; o.y = v[1]; o.z = v[2]; o.w = v[3];
                *(float4*)dst = o;
            } else {
                float2 o; o.x = v[0]; o.y = v[1];
                *(float2*)dst = o;
            }
        }
    }
}

__global__ void count_edges(const int* __restrict__ rels, int* __restrict__ CNT)
{
    int e = blockIdx.x * 256 + threadIdx.x;
    if (e >= T_N) return;
    atomicAdd(CNT + rels[3 * e + 0], 1);
    atomicAdd(CNT + rels[3 * e + 2], 1);
}

__global__ void scatter_pool(const float* __restrict__ T2,
                             const int* __restrict__ rels,
                             float* __restrict__ PO)
{
    int e = blockIdx.x;
    int t = threadIdx.x;            // 256
    int s = rels[e * 3 + 0];
    int o = rels[e * 3 + 2];
#pragma unroll
    for (int u = 0; u < 2; u++) {
        int j = t + u * 256;
        unsafeAtomicAdd(PO + (size_t)s * HH_ + j, T2[(size_t)e * 1536 + j]);
        unsafeAtomicAdd(PO + (size_t)o * HH_ + j, T2[(size_t)e * 1536 + 1024 + j]);
    }
}

__global__ void copy_pred(const float* __restrict__ T2, float* __restrict__ dst)
{
    int i = blockIdx.x * 256 + threadIdx.x;   // float4 index
    if (i >= T_N * HH_ / 4) return;
    int e = i / (HH_ / 4);
    int j = (i % (HH_ / 4)) << 2;
    float4 v = *(const float4*)(T2 + (size_t)e * 1536 + 512 + j);
    *(float4*)(dst + (size_t)e * HH_ + j) = v;
}

template<int TBM, int TBN, int MR, int NR, int MODE>
static inline void G(hipStream_t st, const float* A, int lda,
                     const float* Tab, int KA, int DWc,
                     const int* idx, int idxs,
                     const float* P1v, const float* P2v,
                     const int* rels, const float* badd, const int* CNT,
                     const float* W, const float* bias, int relu_,
                     float* C, int ldc,
                     const float* W_alt, float* C_alt,
                     int M, int N, int K)
{
    int bxHalf = N / TBN;
    dim3 g(bxHalf * (W_alt ? 2 : 1), (M + TBM - 1) / TBM), b(256);
    gemm_k<TBM, TBN, MR, NR, MODE><<<g, b, 0, st>>>(
        A, lda, Tab, KA, DWc, idx, idxs, P1v, P2v, rels, badd, CNT,
        W, bias, relu_, C, ldc, W_alt, C_alt, bxHalf, M, N, K);
}

extern "C" void kernel_launch(void* const* d_in, const int* in_sizes, int n_in,
                              void* d_out, int out_size, void* d_ws, size_t ws_size,
                              hipStream_t stream)
{
    const float* obj_embs  = (const float*)d_in[0];
    const float* pred_embs = (const float*)d_in[2];
    const int*   rels      = (const int*)d_in[4];
    const int*   objs      = (const int*)d_in[5];
    const float* obj_table = (const float*)d_in[6];
    const float* rel_table = (const float*)d_in[7];
    const float* Wf_obj = (const float*)d_in[8];
    const float* bf_obj = (const float*)d_in[9];
    const float* Wf_rel = (const float*)d_in[10];
    const float* bf_rel = (const float*)d_in[11];
    const float* W1a = (const float*)d_in[12];
    const float* b1a = (const float*)d_in[13];
    const float* W1b = (const float*)d_in[14];
    const float* b1b = (const float*)d_in[15];
    const float* W2a = (const float*)d_in[16];
    const float* b2a = (const float*)d_in[17];
    const float* W2b = (const float*)d_in[18];
    const float* b2b = (const float*)d_in[19];
    const float* Ws1a = (const float*)d_in[20];
    const float* bs1a = (const float*)d_in[21];
    const float* Ws1b = (const float*)d_in[22];
    const float* bs1b = (const float*)d_in[23];
    const float* Ws2a = (const float*)d_in[24];
    const float* bs2a = (const float*)d_in[25];
    const float* Ws2b = (const float*)d_in[26];
    const float* bs2b = (const float*)d_in[27];
    float* out = (float*)d_out;

    float* base = (float*)d_ws;
    float* OV = base;                              // 2000*2048
    float* PV = OV + (size_t)O_N * DIN;            // 6000*2048
    float* P1 = PV + (size_t)T_N * DIN;            // 2000*512
    float* P2 = P1 + (size_t)O_N * HH_;            // 2000*512
    float* PP = P2 + (size_t)O_N * HH_;            // 6000*512
    float* T2 = PP + (size_t)T_N * HH_;            // 6000*1536
    float* PO = T2 + (size_t)T_N * 1536;           // 2000*512
    int* CNT = (int*)(PO + (size_t)O_N * HH_);     // 2000 ints

    hipMemsetAsync(CNT, 0, (size_t)O_N * sizeof(int), stream);
    hipLaunchKernelGGL(count_edges, dim3((T_N + 255) / 256), dim3(256), 0, stream,
                       rels, CNT);

    // input projections (concat fused into A-load)
    G<128, 64, 8, 4, 1>(stream, obj_embs, DIN, obj_table, DIN, DW, objs, 1,
                        nullptr, nullptr, nullptr, nullptr, nullptr,
                        Wf_obj, bf_obj, 1, OV, DIN, nullptr, nullptr,
                        O_N, DIN, DIN + DW);
    G<128, 64, 8, 4, 1>(stream, pred_embs, DIN, rel_table, DIN, DW, rels + 1, 3,
                        nullptr, nullptr, nullptr, nullptr, nullptr,
                        Wf_rel, bf_rel, 1, PV, DIN, nullptr, nullptr,
                        T_N, DIN, DIN + DW);

    for (int L = 0; L < 5; L++) {
        const int D = (L == 0) ? DIN : HH_;
        const float* w1a  = (L == 0) ? W1a : (Ws1a + (size_t)(L - 1) * 3 * HH_ * HH_);
        const float* bb1a = (L == 0) ? b1a : (bs1a + (size_t)(L - 1) * HH_);
        const float* w1b  = (L == 0) ? W1b : (Ws1b + (size_t)(L - 1) * HH_ * 1536);
        const float* bb1b = (L == 0) ? b1b : (bs1b + (size_t)(L - 1) * 1536);
        const float* w2a  = (L == 0) ? W2a : (Ws2a + (size_t)(L - 1) * HH_ * HH_);
        const float* bb2a = (L == 0) ? b2a : (bs2a + (size_t)(L - 1) * HH_);
        const float* w2b  = (L == 0) ? W2b : (Ws2b + (size_t)(L - 1) * HH_ * DG);
        const float* bb2b = (L == 0) ? b2b : (bs2b + (size_t)(L - 1) * DG);
        const float* w1a_top = w1a;
        const float* w1a_mid = w1a + (size_t)D * HH_;
        const float* w1a_bot = w1a + (size_t)2 * D * HH_;

        // P1 = OV@top, P2 = OV@bot — pair dispatch (shared A)
        G<128, 64, 8, 4, 0>(stream, OV, D, nullptr, 0, 0, nullptr, 0,
                            nullptr, nullptr, nullptr, nullptr, nullptr,
                            w1a_top, nullptr, 0, P1, HH_, w1a_bot, P2,
                            O_N, HH_, D);
        // PP = PV@mid
        G<128, 64, 8, 4, 0>(stream, PV, D, nullptr, 0, 0, nullptr, 0,
                            nullptr, nullptr, nullptr, nullptr, nullptr,
                            w1a_mid, nullptr, 0, PP, HH_, nullptr, nullptr,
                            T_N, HH_, D);

        // t2 = relu( relu(P1[s]+PP+P2[o]+b1a) @ W1b + b1b )
        G<128, 64, 8, 4, 2>(stream, PP, HH_, nullptr, 0, 0, nullptr, 0,
                            P1, P2, rels, bb1a, nullptr,
                            w1b, bb1b, 1, T2, 1536, nullptr, nullptr,
                            T_N, 1536, HH_);

        // pooling
        hipMemsetAsync(PO, 0, (size_t)O_N * HH_ * sizeof(float), stream);
        hipLaunchKernelGGL(scatter_pool, dim3(T_N), dim3(256), 0, stream,
                           T2, rels, PO);

        // obj MLP2 (small-M config) — pool-div fused
        G<64, 32, 4, 2, 3>(stream, PO, HH_, nullptr, 0, 0, nullptr, 0,
                           nullptr, nullptr, nullptr, nullptr, CNT,
                           w2a, bb2a, 1, P1, HH_, nullptr, nullptr,
                           O_N, HH_, HH_);
        float* objDst = (L == 4) ? out : OV;
        G<64, 32, 4, 2, 0>(stream, P1, HH_, nullptr, 0, 0, nullptr, 0,
                           nullptr, nullptr, nullptr, nullptr, nullptr,
                           w2b, bb2b, 1, objDst, HH_, nullptr, nullptr,
                           O_N, DG, HH_);

        float* predDst = (L == 4) ? (out + (size_t)O_N * DG) : PV;
        hipLaunchKernelGGL(copy_pred, dim3((T_N * HH_ / 4 + 255) / 256), dim3(256), 0, stream,
                           T2, predDst);
    }
}

// Round 6
// 2820.924 us; speedup vs baseline: 2.5637x; 1.2592x over previous
//
#include <hip/hip_runtime.h>

#define O_N 2000
#define T_N 6000
#define DIN 2048
#define DW  300
#define DG  512
#define HH_ 512

typedef __attribute__((ext_vector_type(8)))  short short8;
typedef __attribute__((ext_vector_type(16))) float f32x16;
typedef unsigned short u16;

__device__ __forceinline__ float4 ld4(const float* p) { return *(const float4*)p; }

// ---- bf16 split-3 helpers (RNE) ----
__device__ __forceinline__ u16 rbf(float x) {
    unsigned int u = __float_as_uint(x);
    u += 0x7FFFu + ((u >> 16) & 1u);
    return (u16)(u >> 16);
}
__device__ __forceinline__ float fbf(u16 h) {
    return __uint_as_float((unsigned int)h << 16);
}
__device__ __forceinline__ void split3(float x, short& h, short& m, short& l) {
    u16 a = rbf(x);
    float r = x - fbf(a);
    u16 b = rbf(r);
    r -= fbf(b);
    u16 c = rbf(r);
    h = (short)a; m = (short)b; l = (short)c;
}

// =====================================================================
// MFMA GEMM: C = act(A @ B + bias) with A,B given as 3 bf16 planes
// (hi/mid/lo), chunk-major layout [K/8][Mp][8] (A) / [K/8][N][8] (B).
// 6 MFMA products: hh -> acc_hi ; hm, mh, hl, mm, lh -> acc_lo.
// Block 256 = 4 waves (2x2), wave tile 64 x (BN/2), 32x32x16 MFMA.
// Double-buffered LDS, one barrier per K=16 tile.
// Optional fp32 C out and/or bf16-plane out (for the next GEMM's A).
// Pair mode: gridDim.x doubled; bx >= nbx uses Bp2/C2/Op2.
// =====================================================================
template<int BM, int BN>
__global__ __launch_bounds__(256, 2) void gemm_mx(
    const u16* __restrict__ Ap, int MpA,
    const u16* __restrict__ Bp, int N, int KC, int M,
    const float* __restrict__ bias, int doRelu,
    float* __restrict__ C, int ldc,
    u16* __restrict__ Op, int MpO,
    const u16* __restrict__ Bp2, float* __restrict__ C2, u16* __restrict__ Op2,
    int nbx)
{
    static_assert(BM == 128, "BM=128");
    constexpr int WM = 64, WN = BN / 2;
    constexpr int FI = 2, FJ = WN / 32;
    constexpr int UA = 6 * BM;            // 16B staging units per tile (A)
    constexpr int UB = 6 * BN;
    constexpr int NI = (UA + UB) / 64;    // staging instructions per tile
    constexpr int II = (NI + 3) / 4;      // per wave
    constexpr int BUF = (BM + BN) * 48;   // ushorts per LDS buffer
    __shared__ u16 sm[2 * BUF];

    const int tid = threadIdx.x;
    const int w = tid >> 6, lane = tid & 63;
    const int ln31 = lane & 31, lq = lane >> 5;

    int bx = blockIdx.x;
    const u16* Bpl = Bp; float* Cl = C; u16* Opl = Op;
    if (bx >= nbx) { bx -= nbx; Bpl = Bp2; Cl = C2; Opl = Op2; }
    const int n0 = bx * BN, m0 = blockIdx.y * BM;
    const long psA = (long)KC * MpA * 8;
    const long psB = (long)KC * N * 8;

    // ---- staging assignment (per-wave instructions, 64 rows x 16B each) ----
    const u16* gb[II]; int gstep[II]; int lo[II]; bool gv[II];
#pragma unroll
    for (int ii = 0; ii < II; ii++) {
        int n = w + 4 * ii;
        gv[ii] = n < NI;
        int nn = gv[ii] ? n : 0;
        int u0 = nn * 64;
        bool isA = u0 < UA;
        int uu = isA ? u0 : u0 - UA;
        int dim = isA ? BM : BN;
        int row0 = uu % dim, pq = uu / dim;
        int q = pq & 1, p = pq >> 1;
        const u16* pb = (isA ? Ap : Bpl) + (long)p * (isA ? psA : psB);
        int mp = isA ? MpA : N;
        gb[ii] = pb + ((long)q * mp + (isA ? m0 : n0) + row0 + lane) * 8;
        gstep[ii] = mp * 16;              // ushorts per tile (2 chunks)
        // LDS dest mirrors the global source: per-lane row offset included.
        lo[ii] = (isA ? (pq * BM + row0) : (6 * BM + pq * BN + row0)) * 8 + lane * 8;
    }

    f32x16 ah[FI][FJ], al[FI][FJ];
#pragma unroll
    for (int fi = 0; fi < FI; fi++)
#pragma unroll
        for (int fj = 0; fj < FJ; fj++)
#pragma unroll
            for (int r = 0; r < 16; r++) { ah[fi][fj][r] = 0.f; al[fi][fj][r] = 0.f; }

    const int T = KC >> 1;
    short8 pf[II];
#pragma unroll
    for (int ii = 0; ii < II; ii++) if (gv[ii]) pf[ii] = *(const short8*)(gb[ii]);
#pragma unroll
    for (int ii = 0; ii < II; ii++) if (gv[ii]) *(short8*)(sm + lo[ii]) = pf[ii];
    __syncthreads();

    for (int t = 0; t < T; t++) {
        const int cb = (t & 1) * BUF, nb2 = ((t + 1) & 1) * BUF;
        const bool more = (t + 1) < T;
        if (more) {
#pragma unroll
            for (int ii = 0; ii < II; ii++)
                if (gv[ii]) pf[ii] = *(const short8*)(gb[ii] + (long)(t + 1) * gstep[ii]);
        }
        const u16* ab = sm + cb;
        const u16* bb = ab + 6 * BM * 8;
        short8 af[FI][3];
#pragma unroll
        for (int fi = 0; fi < FI; fi++)
#pragma unroll
            for (int p = 0; p < 3; p++)
                af[fi][p] = *(const short8*)(ab + ((p * 2 + lq) * BM + (w >> 1) * WM + fi * 32 + ln31) * 8);
#pragma unroll
        for (int fj = 0; fj < FJ; fj++) {
            const int rB = (w & 1) * WN + fj * 32 + ln31;
            short8 bh = *(const short8*)(bb + ((0 * 2 + lq) * BN + rB) * 8);
            short8 bm_ = *(const short8*)(bb + ((1 * 2 + lq) * BN + rB) * 8);
            short8 bl = *(const short8*)(bb + ((2 * 2 + lq) * BN + rB) * 8);
#pragma unroll
            for (int fi = 0; fi < FI; fi++) {
                ah[fi][fj] = __builtin_amdgcn_mfma_f32_32x32x16_bf16(af[fi][0], bh,  ah[fi][fj], 0, 0, 0);
                al[fi][fj] = __builtin_amdgcn_mfma_f32_32x32x16_bf16(af[fi][0], bm_, al[fi][fj], 0, 0, 0);
                al[fi][fj] = __builtin_amdgcn_mfma_f32_32x32x16_bf16(af[fi][1], bh,  al[fi][fj], 0, 0, 0);
                al[fi][fj] = __builtin_amdgcn_mfma_f32_32x32x16_bf16(af[fi][0], bl,  al[fi][fj], 0, 0, 0);
                al[fi][fj] = __builtin_amdgcn_mfma_f32_32x32x16_bf16(af[fi][1], bm_, al[fi][fj], 0, 0, 0);
                al[fi][fj] = __builtin_amdgcn_mfma_f32_32x32x16_bf16(af[fi][2], bh,  al[fi][fj], 0, 0, 0);
            }
        }
        if (more) {
#pragma unroll
            for (int ii = 0; ii < II; ii++)
                if (gv[ii]) *(short8*)(sm + nb2 + lo[ii]) = pf[ii];
        }
        __syncthreads();
    }

    // ---- epilogue ----
    float* bounce = (float*)sm + w * 1184;     // 32x36 floats, per-wave region
    const long psO = (long)N * MpO;            // ushorts per out plane
#pragma unroll
    for (int fi = 0; fi < FI; fi++) {
#pragma unroll
        for (int fj = 0; fj < FJ; fj++) {
            const int colBase = n0 + (w & 1) * WN + fj * 32;
            const int rowBase = m0 + (w >> 1) * WM + fi * 32;
            float bv = bias ? bias[colBase + ln31] : 0.f;
            float v[16];
#pragma unroll
            for (int r = 0; r < 16; r++) {
                float x = ah[fi][fj][r] + (al[fi][fj][r] + bv);
                if (doRelu) x = fmaxf(x, 0.f);
                v[r] = x;
            }
            if (Cl) {
#pragma unroll
                for (int r = 0; r < 16; r++) {
                    int row = rowBase + (r & 3) + 8 * (r >> 2) + 4 * lq;
                    if (row < M)
                        Cl[(long)row * ldc + colBase + ln31] = v[r];
                }
            }
            if (Opl) {
#pragma unroll
                for (int r = 0; r < 16; r++)
                    bounce[((r & 3) + 8 * (r >> 2) + 4 * lq) * 36 + ln31] = v[r];
#pragma unroll
                for (int u = 0; u < 2; u++) {
                    int urow = ln31, uc = lq + 2 * u;
                    const float* rp = bounce + urow * 36 + uc * 8;
                    short8 h8, m8, l8;
#pragma unroll
                    for (int j = 0; j < 8; j++) {
                        short a, b, c2; split3(rp[j], a, b, c2);
                        h8[j] = a; m8[j] = b; l8[j] = c2;
                    }
                    long cIdx = (long)((colBase + uc * 8) >> 3);
                    long base = (cIdx * MpO + rowBase + urow) * 8;
                    *(short8*)(Opl + base) = h8;
                    *(short8*)(Opl + psO + base) = m8;
                    *(short8*)(Opl + 2 * psO + base) = l8;
                }
            }
        }
    }
}

// ---- split weights: W [K][N] fp32 -> 3 planes [K/8][N][8] bf16 ----
__global__ __launch_bounds__(256) void split_b(
    const float* __restrict__ W, int K, int N, int KC,
    u16* __restrict__ Op)
{
    __shared__ float tl[64][65];
    const int tid = threadIdx.x;
    const int n0 = blockIdx.x * 64, k0 = blockIdx.y * 64;
    const long ps = (long)KC * N * 8;
#pragma unroll
    for (int l = 0; l < 4; l++) {
        int k = (tid >> 4) + l * 16;
        int nn = (tid & 15) << 2;
        float4 v = make_float4(0.f, 0.f, 0.f, 0.f);
        if (k0 + k < K) v = ld4(W + (long)(k0 + k) * N + n0 + nn);
        tl[k][nn] = v.x; tl[k][nn + 1] = v.y; tl[k][nn + 2] = v.z; tl[k][nn + 3] = v.w;
    }
    __syncthreads();
#pragma unroll
    for (int l = 0; l < 2; l++) {
        int u = tid + l * 256;
        int n = u & 63, c = u >> 6;
        short8 h8, m8, l8;
#pragma unroll
        for (int j = 0; j < 8; j++) {
            short a, b, c2; split3(tl[c * 8 + j][n], a, b, c2);
            h8[j] = a; m8[j] = b; l8[j] = c2;
        }
        long base = ((long)(k0 / 8 + c) * N + n0 + n) * 8;
        *(short8*)(Op + base) = h8;
        *(short8*)(Op + ps + base) = m8;
        *(short8*)(Op + 2 * ps + base) = l8;
    }
}

__device__ __forceinline__ void store_planes(u16* Op, long ps, long base, const float* x)
{
    short8 h8, m8, l8;
#pragma unroll
    for (int j = 0; j < 8; j++) {
        short a, b, c2; split3(x[j], a, b, c2);
        h8[j] = a; m8[j] = b; l8[j] = c2;
    }
    *(short8*)(Op + base) = h8;
    *(short8*)(Op + ps + base) = m8;
    *(short8*)(Op + 2 * ps + base) = l8;
}

// ---- concat(A | Tab[idx]) fp32 -> planes [KC][Mp][8] ----
__global__ __launch_bounds__(256) void split_concat_a(
    const float* __restrict__ E, int ldE, int KA,
    const float* __restrict__ Tab, int DWc,
    const int* __restrict__ idx, int idxStride,
    int mBase, int Mvalid, int Mp, int KC,
    u16* __restrict__ Op)
{
    int m = blockIdx.x * 256 + threadIdx.x;
    if (m >= Mp) return;
    int c = blockIdx.y;
    int gm = mBase + m;
    float x[8];
    if (gm >= Mvalid) {
#pragma unroll
        for (int j = 0; j < 8; j++) x[j] = 0.f;
    } else {
        int k0 = c * 8;
        if (k0 + 8 <= KA) {
            float4 a = ld4(E + (long)gm * ldE + k0);
            float4 b = ld4(E + (long)gm * ldE + k0 + 4);
            x[0] = a.x; x[1] = a.y; x[2] = a.z; x[3] = a.w;
            x[4] = b.x; x[5] = b.y; x[6] = b.z; x[7] = b.w;
        } else {
            const float* tr = Tab + (long)idx[(long)gm * idxStride] * DWc;
#pragma unroll
            for (int j = 0; j < 8; j++) {
                int k = k0 + j;
                x[j] = (k < KA) ? E[(long)gm * ldE + k]
                                : ((k - KA) < DWc ? tr[k - KA] : 0.f);
            }
        }
    }
    store_planes(Op, (long)KC * Mp * 8, ((long)c * Mp + m) * 8, x);
}

// ---- edge combine: relu(P1[s]+PP+P2[o]+b1a) -> planes (KC=64) ----
__global__ __launch_bounds__(256) void edge_planes(
    const float* __restrict__ PPv, const float* __restrict__ P1v,
    const float* __restrict__ P2v, const int* __restrict__ rels,
    const float* __restrict__ b1a, int Mp, u16* __restrict__ Op)
{
    int m = blockIdx.x * 256 + threadIdx.x;
    if (m >= Mp) return;
    int c = blockIdx.y;
    float x[8];
    if (m >= T_N) {
#pragma unroll
        for (int j = 0; j < 8; j++) x[j] = 0.f;
    } else {
        int s = rels[3 * m], o = rels[3 * m + 2];
        const float* pp = PPv + (long)m * HH_ + c * 8;
        const float* p1 = P1v + (long)s * HH_ + c * 8;
        const float* p2 = P2v + (long)o * HH_ + c * 8;
        const float* bb = b1a + c * 8;
#pragma unroll
        for (int j = 0; j < 8; j++)
            x[j] = fmaxf(pp[j] + p1[j] + p2[j] + bb[j], 0.f);
    }
    store_planes(Op, (long)64 * Mp * 8, ((long)c * Mp + m) * 8, x);
}

// ---- pooled/cnt -> planes (KC=64) ----
__global__ __launch_bounds__(256) void pool_planes(
    const float* __restrict__ PO, const int* __restrict__ CNT,
    int Mp, u16* __restrict__ Op)
{
    int m = blockIdx.x * 256 + threadIdx.x;
    if (m >= Mp) return;
    int c = blockIdx.y;
    float x[8];
    if (m >= O_N) {
#pragma unroll
        for (int j = 0; j < 8; j++) x[j] = 0.f;
    } else {
        int cc = CNT[m]; float cf = 1.f / (float)(cc < 1 ? 1 : cc);
#pragma unroll
        for (int j = 0; j < 8; j++) x[j] = PO[(long)m * HH_ + c * 8 + j] * cf;
    }
    store_planes(Op, (long)64 * Mp * 8, ((long)c * Mp + m) * 8, x);
}

// ---- T2 mid slice -> PV planes (KC=64) ----
__global__ __launch_bounds__(256) void predcopy_planes(
    const float* __restrict__ T2, int Mp, u16* __restrict__ Op)
{
    int m = blockIdx.x * 256 + threadIdx.x;
    if (m >= Mp) return;
    int c = blockIdx.y;
    float x[8];
    if (m >= T_N) {
#pragma unroll
        for (int j = 0; j < 8; j++) x[j] = 0.f;
    } else {
#pragma unroll
        for (int j = 0; j < 8; j++) x[j] = T2[(long)m * 1536 + 512 + c * 8 + j];
    }
    store_planes(Op, (long)64 * Mp * 8, ((long)c * Mp + m) * 8, x);
}

__global__ void predcopy_f32(const float* __restrict__ T2, float* __restrict__ dst)
{
    int i = blockIdx.x * 256 + threadIdx.x;   // float4 index
    if (i >= T_N * HH_ / 4) return;
    int e = i / (HH_ / 4);
    int j = (i % (HH_ / 4)) << 2;
    float4 v = ld4(T2 + (long)e * 1536 + 512 + j);
    *(float4*)(dst + (long)e * HH_ + j) = v;
}

__global__ void count_edges(const int* __restrict__ rels, int* __restrict__ CNT)
{
    int e = blockIdx.x * 256 + threadIdx.x;
    if (e >= T_N) return;
    atomicAdd(CNT + rels[3 * e + 0], 1);
    atomicAdd(CNT + rels[3 * e + 2], 1);
}

__global__ void scatter_pool(const float* __restrict__ T2,
                             const int* __restrict__ rels,
                             float* __restrict__ PO)
{
    int e = blockIdx.x;
    int t = threadIdx.x;            // 256
    int s = rels[e * 3 + 0];
    int o = rels[e * 3 + 2];
#pragma unroll
    for (int u = 0; u < 2; u++) {
        int j = t + u * 256;
        unsafeAtomicAdd(PO + (long)s * HH_ + j, T2[(long)e * 1536 + j]);
        unsafeAtomicAdd(PO + (long)o * HH_ + j, T2[(long)e * 1536 + 1024 + j]);
    }
}

// ---- host-side helpers ----
template<int BM, int BN>
static inline void GX(hipStream_t st, const u16* Ap, int MpA,
                      const u16* Bp, int N, int KC, int M,
                      const float* bias, int relu_,
                      float* C, int ldc, u16* Op, int MpO,
                      const u16* Bp2, float* C2, u16* Op2)
{
    int nbx = N / BN;
    int pair = (Bp2 != nullptr) ? 2 : 1;
    dim3 g(nbx * pair, MpA / BM), b(256);
    gemm_mx<BM, BN><<<g, b, 0, st>>>(Ap, MpA, Bp, N, KC, M, bias, relu_,
                                     C, ldc, Op, MpO, Bp2, C2, Op2, nbx);
}

static inline void SB(hipStream_t st, const float* W, int K, int N, int KC, u16* Op)
{
    dim3 g(N / 64, KC / 8), b(256);
    split_b<<<g, b, 0, st>>>(W, K, N, KC, Op);
}

extern "C" void kernel_launch(void* const* d_in, const int* in_sizes, int n_in,
                              void* d_out, int out_size, void* d_ws, size_t ws_size,
                              hipStream_t stream)
{
    const float* obj_embs  = (const float*)d_in[0];
    const float* pred_embs = (const float*)d_in[2];
    const int*   rels      = (const int*)d_in[4];
    const int*   objs      = (const int*)d_in[5];
    const float* obj_table = (const float*)d_in[6];
    const float* rel_table = (const float*)d_in[7];
    const float* Wf_obj = (const float*)d_in[8];
    const float* bf_obj = (const float*)d_in[9];
    const float* Wf_rel = (const float*)d_in[10];
    const float* bf_rel = (const float*)d_in[11];
    const float* W1a = (const float*)d_in[12];
    const float* b1a = (const float*)d_in[13];
    const float* W1b = (const float*)d_in[14];
    const float* b1b = (const float*)d_in[15];
    const float* W2a = (const float*)d_in[16];
    const float* b2a = (const float*)d_in[17];
    const float* W2b = (const float*)d_in[18];
    const float* b2b = (const float*)d_in[19];
    const float* Ws1a = (const float*)d_in[20];
    const float* bs1a = (const float*)d_in[21];
    const float* Ws1b = (const float*)d_in[22];
    const float* bs1b = (const float*)d_in[23];
    const float* Ws2a = (const float*)d_in[24];
    const float* bs2a = (const float*)d_in[25];
    const float* Ws2b = (const float*)d_in[26];
    const float* bs2b = (const float*)d_in[27];
    float* out = (float*)d_out;

    // ---- workspace layout (bytes), total ~119.6 MB ----
    unsigned char* B8 = (unsigned char*)d_ws;
    constexpr size_t S1O  = 0;                     // concat-A planes    29,097,984
    constexpr size_t S2O  = 29097984;              // chunk-out planes   25,165,824
    constexpr size_t S3AO = 54263808;              // Wf B planes        29,097,984
    constexpr size_t ZSZ  = 86507520;              // overlay-zone size
    //   overlays inside zone (live only after L0's PP GEMM):
    constexpr size_t T2O  = 0;                     // 36,864,000
    constexpr size_t TTO  = 36864000;              // 18,481,152 (TTp / Hp)
    constexpr size_t PVO  = 55345152;              // 18,481,152 (PVpS)
    constexpr size_t PLO  = 73826304;              //  6,291,456 (PLp)
    constexpr size_t OVO  = 80117760;              //  6,291,456 (OVpS)
    constexpr size_t S3BO = ZSZ;                   //  6,291,456 (B slot b)
    constexpr size_t S3CO = S3BO + 6291456;        //  6,291,456 (B slot c)
    constexpr size_t PPO  = S3CO + 6291456;        // 12,288,000
    constexpr size_t P1O  = PPO + 12288000;        //  4,096,000 (also PO)
    constexpr size_t P2O  = P1O + 4096000;         //  4,096,000
    constexpr size_t CNO  = P2O + 4096000;         //  8,000

    u16* S1  = (u16*)(B8 + S1O);
    u16* S2  = (u16*)(B8 + S2O);
    u16* S3A = (u16*)(B8 + S3AO);
    u16* S3B = (u16*)(B8 + S3BO);
    u16* S3C = (u16*)(B8 + S3CO);
    float* T2 = (float*)(B8 + T2O);
    u16* TTp  = (u16*)(B8 + TTO);
    u16* Hp   = (u16*)(B8 + TTO);                 // overlays TTp (disjoint in time)
    u16* PVp  = (u16*)(B8 + PVO);
    u16* PLp  = (u16*)(B8 + PLO);
    u16* OVp  = (u16*)(B8 + OVO);
    float* PP = (float*)(B8 + PPO);
    float* P1 = (float*)(B8 + P1O);
    float* P2 = (float*)(B8 + P2O);
    float* PO = P1;                                // reuse (P1 dead after edge)
    int* CNT  = (int*)(B8 + CNO);

    // ---- edge counts (fixed for whole call) ----
    hipMemsetAsync(CNT, 0, O_N * sizeof(int), stream);
    hipLaunchKernelGGL(count_edges, dim3((T_N + 255) / 256), dim3(256), 0, stream, rels, CNT);

    // ================= projections + layer-0 front =================
    // obj: OV-chunk planes -> P1/P2 via W1a top/bot
    SB(stream, Wf_obj, DIN + DW, DIN, 296, S3A);
    {
        dim3 g(8, 296), b(256);
        split_concat_a<<<g, b, 0, stream>>>(obj_embs, DIN, DIN, obj_table, DW,
                                            objs, 1, 0, O_N, 2048, 296, S1);
    }
    GX<128, 128>(stream, S1, 2048, S3A, DIN, 296, O_N, bf_obj, 1,
                 nullptr, 0, S2, 2048, nullptr, nullptr, nullptr);
    SB(stream, W1a, DIN, HH_, 256, S3B);                       // top (L0 K=2048)
    SB(stream, W1a + (size_t)2 * DIN * HH_, DIN, HH_, 256, S3C); // bot
    GX<128, 64>(stream, S2, 2048, S3B, HH_, 256, O_N, nullptr, 0,
                P1, HH_, nullptr, 0, S3C, P2, nullptr);
    // pred, M-chunked: proj -> PV-chunk planes -> PP via W1a mid
    SB(stream, Wf_rel, DIN + DW, DIN, 296, S3A);
    SB(stream, W1a + (size_t)DIN * HH_, DIN, HH_, 256, S3B);   // mid
    for (int ch = 0; ch < 3; ch++) {
        int ch0 = ch * 2048;
        int mp  = (ch == 2) ? 1920 : 2048;
        int mv  = (ch == 2) ? 1904 : 2048;
        dim3 g((mp + 255) / 256, 296), b(256);
        split_concat_a<<<g, b, 0, stream>>>(pred_embs, DIN, DIN, rel_table, DW,
                                            rels + 1, 3, ch0, T_N, mp, 296, S1);
        GX<128, 128>(stream, S1, mp, S3A, DIN, 296, mv, bf_rel, 1,
                     nullptr, 0, S2, mp, nullptr, nullptr, nullptr);
        GX<128, 64>(stream, S2, mp, S3B, HH_, 256, mv, nullptr, 0,
                    PP + (size_t)ch0 * HH_, HH_, nullptr, 0,
                    nullptr, nullptr, nullptr);
    }

    // ================= 5 conv layers =================
    for (int L = 0; L < 5; L++) {
        const float* bb1a = (L == 0) ? b1a : (bs1a + (size_t)(L - 1) * HH_);
        const float* w1b  = (L == 0) ? W1b : (Ws1b + (size_t)(L - 1) * HH_ * 1536);
        const float* bb1b = (L == 0) ? b1b : (bs1b + (size_t)(L - 1) * 1536);
        const float* w2a  = (L == 0) ? W2a : (Ws2a + (size_t)(L - 1) * HH_ * HH_);
        const float* bb2a = (L == 0) ? b2a : (bs2a + (size_t)(L - 1) * HH_);
        const float* w2b  = (L == 0) ? W2b : (Ws2b + (size_t)(L - 1) * HH_ * DG);
        const float* bb2b = (L == 0) ? b2b : (bs2b + (size_t)(L - 1) * DG);

        if (L > 0) {
            const float* w1a = Ws1a + (size_t)(L - 1) * 3 * HH_ * HH_;
            SB(stream, w1a, HH_, HH_, 64, S3B);                       // top
            SB(stream, w1a + (size_t)2 * HH_ * HH_, HH_, HH_, 64, S3C); // bot
            GX<128, 64>(stream, OVp, 2048, S3B, HH_, 64, O_N, nullptr, 0,
                        P1, HH_, nullptr, 0, S3C, P2, nullptr);
            SB(stream, w1a + (size_t)HH_ * HH_, HH_, HH_, 64, S3B);   // mid
            GX<128, 64>(stream, PVp, 6016, S3B, HH_, 64, T_N, nullptr, 0,
                        PP, HH_, nullptr, 0, nullptr, nullptr, nullptr);
        }

        // edge combine -> TT planes
        {
            dim3 g(24, 64), b(256);
            edge_planes<<<g, b, 0, stream>>>(PP, P1, P2, rels, bb1a, 6016, TTp);
        }
        // t2 = relu(TT @ W1b + b1b)
        SB(stream, w1b, HH_, 1536, 64, S3C);
        GX<128, 128>(stream, TTp, 6016, S3C, 1536, 64, T_N, bb1b, 1,
                     T2, 1536, nullptr, 0, nullptr, nullptr, nullptr);
        // pooling
        hipMemsetAsync(PO, 0, (size_t)O_N * HH_ * sizeof(float), stream);
        hipLaunchKernelGGL(scatter_pool, dim3(T_N), dim3(256), 0, stream, T2, rels, PO);
        {
            dim3 g(8, 64), b(256);
            pool_planes<<<g, b, 0, stream>>>(PO, CNT, 2048, PLp);
        }
        // obj MLP2
        SB(stream, w2a, HH_, HH_, 64, S3B);
        GX<128, 64>(stream, PLp, 2048, S3B, HH_, 64, O_N, bb2a, 1,
                    nullptr, 0, Hp, 2048, nullptr, nullptr, nullptr);
        SB(stream, w2b, HH_, DG, 64, S3C);
        if (L < 4) {
            GX<128, 64>(stream, Hp, 2048, S3C, DG, 64, O_N, bb2b, 1,
                        nullptr, 0, OVp, 2048, nullptr, nullptr, nullptr);
            dim3 g(24, 64), b(256);
            predcopy_planes<<<g, b, 0, stream>>>(T2, 6016, PVp);
        } else {
            GX<128, 64>(stream, Hp, 2048, S3C, DG, 64, O_N, bb2b, 1,
                        out, DG, nullptr, 0, nullptr, nullptr, nullptr);
            hipLaunchKernelGGL(predcopy_f32, dim3((T_N * HH_ / 4 + 255) / 256),
                               dim3(256), 0, stream, T2, out + (size_t)O_N * DG);
        }
    }
}